// Round 1
// baseline (1374.288 us; speedup 1.0000x reference)
//
#include <hip/hip_runtime.h>

#define NROIS 512
#define NEDGES 262144

// edge_index may arrive as int64 (reference dtype) or int32 (harness downcast).
// For int64 little-endian with values in [0,512), all odd 32-bit words of the
// first 64 elements are zero; for int32 they are random node ids (P(all 0)~0).
__device__ __forceinline__ int detect_i64(const unsigned* __restrict__ er) {
    unsigned acc = 0;
#pragma unroll
    for (int i = 0; i < 64; ++i) acc |= er[2 * i + 1];
    return acc == 0u;
}

__global__ __launch_bounds__(256) void zero_ws(float* __restrict__ p, int n) {
    int t = blockIdx.x * 256 + threadIdx.x;
    if (t < n) p[t] = 0.f;
}

// One thread per edge: compute per-edge weight matrix on the fly, form the
// message, atomically accumulate into ssum[dst]. lw layout: [6][CIN*COUT].
template <int CIN, int COUT, bool DO_CNT>
__global__ __launch_bounds__(256) void edge_kernel(
    const float* __restrict__ ea, const unsigned* __restrict__ er,
    const float* __restrict__ lw, const float* __restrict__ lb,
    const float* __restrict__ hin, float* __restrict__ ssum,
    float* __restrict__ cnt)
{
    __shared__ int s_l;
    if (threadIdx.x == 0) s_l = detect_i64(er);
    __syncthreads();
    const bool L = (s_l != 0);

    const int e = blockIdx.x * 256 + threadIdx.x;
    int src, dst;
    if (L) { src = (int)er[2 * e]; dst = (int)er[2 * NEDGES + 2 * e]; }
    else   { src = (int)er[e];     dst = (int)er[NEDGES + e]; }

    // edge_attr row: 6 floats, 8B-aligned (e*24 bytes) -> three float2 loads
    const float2* eap = reinterpret_cast<const float2*>(ea + e * 6);
    const float2 a01 = eap[0], a23 = eap[1], a45 = eap[2];
    const float a[6] = {a01.x, a01.y, a23.x, a23.y, a45.x, a45.y};

    if (DO_CNT) atomicAdd(&cnt[dst], 1.0f);

    float msg[COUT];
#pragma unroll
    for (int o = 0; o < COUT; ++o) msg[o] = 0.f;

    for (int i = 0; i < CIN; ++i) {
        const float hs = hin[src * CIN + i];
#pragma unroll
        for (int o = 0; o < COUT; ++o) {
            float t = lb[i * COUT + o];
#pragma unroll
            for (int v = 0; v < 6; ++v)
                t = fmaf(a[v], lw[v * (CIN * COUT) + i * COUT + o], t);
            msg[o] = fmaf(hs, fmaxf(t, 0.f), msg[o]);
        }
    }

    float* __restrict__ sd = ssum + dst * COUT;
#pragma unroll
    for (int o = 0; o < COUT; ++o) atomicAdd(&sd[o], msg[o]);
}

// h_out[i,o] = relu(ssum[i,o]/max(cnt[i],1) + sum_k hin[i,k]*root[k,o] + b[o])
template <int CIN, int COUT>
__global__ __launch_bounds__(256) void node_kernel(
    const float* __restrict__ hin, const float* __restrict__ ssum,
    const float* __restrict__ cnt, const float* __restrict__ root,
    const float* __restrict__ b, float* __restrict__ hout)
{
    int t = blockIdx.x * 256 + threadIdx.x;
    if (t >= NROIS * COUT) return;
    int i = t / COUT, o = t - i * COUT;
    float c = fmaxf(cnt[i], 1.f);
    float acc = ssum[t] / c + b[o];
#pragma unroll
    for (int k = 0; k < CIN; ++k)
        acc = fmaf(hin[i * CIN + k], root[k * COUT + o], acc);
    hout[t] = fmaxf(acc, 0.f);
}

// cbt[i,j] = sum_k |h[i,k]-h[j,k]|, h: [512,5] staged in LDS, block per row i
__global__ __launch_bounds__(256) void cbt_kernel(const float* __restrict__ h,
                                                  float* __restrict__ out)
{
    __shared__ float sh[NROIS * 5];
    for (int t = threadIdx.x; t < NROIS * 5; t += 256) sh[t] = h[t];
    __syncthreads();
    const int i = blockIdx.x;
    float hi[5];
#pragma unroll
    for (int k = 0; k < 5; ++k) hi[k] = sh[i * 5 + k];
    for (int j = threadIdx.x; j < NROIS; j += 256) {
        float s = 0.f;
#pragma unroll
        for (int k = 0; k < 5; ++k) s += fabsf(hi[k] - sh[j * 5 + k]);
        out[i * NROIS + j] = s;
    }
}

extern "C" void kernel_launch(void* const* d_in, const int* in_sizes, int n_in,
                              void* d_out, int out_size, void* d_ws, size_t ws_size,
                              hipStream_t stream)
{
    const float*    x     = (const float*)d_in[0];
    const float*    ea    = (const float*)d_in[1];
    const unsigned* er    = (const unsigned*)d_in[2];
    const float*    lw1   = (const float*)d_in[3];
    const float*    lb1   = (const float*)d_in[4];
    const float*    root1 = (const float*)d_in[5];
    const float*    b1    = (const float*)d_in[6];
    const float*    lw2   = (const float*)d_in[7];
    const float*    lb2   = (const float*)d_in[8];
    const float*    root2 = (const float*)d_in[9];
    const float*    b2    = (const float*)d_in[10];
    const float*    lw3   = (const float*)d_in[11];
    const float*    lb3   = (const float*)d_in[12];
    const float*    root3 = (const float*)d_in[13];
    const float*    b3    = (const float*)d_in[14];

    float* ws  = (float*)d_ws;
    float* cnt = ws;                 // 512
    float* s1  = cnt + NROIS;        // 512*36
    float* s2  = s1 + NROIS * 36;    // 512*24
    float* s3  = s2 + NROIS * 24;    // 512*5
    float* h1  = s3 + NROIS * 5;     // 512*36
    float* h2  = h1 + NROIS * 36;    // 512*24
    float* h3  = h2 + NROIS * 24;    // 512*5

    const int nzero = NROIS * (1 + 36 + 24 + 5);   // 33792
    zero_ws<<<(nzero + 255) / 256, 256, 0, stream>>>(ws, nzero);

    const int EB = NEDGES / 256;  // 1024 blocks

    // Layer 1 (cin=1, cout=36), hin = x
    edge_kernel<1, 36, true><<<EB, 256, 0, stream>>>(ea, er, lw1, lb1, x, s1, cnt);
    node_kernel<1, 36><<<(NROIS * 36 + 255) / 256, 256, 0, stream>>>(x, s1, cnt, root1, b1, h1);

    // Layer 2 (cin=36, cout=24)
    edge_kernel<36, 24, false><<<EB, 256, 0, stream>>>(ea, er, lw2, lb2, h1, s2, cnt);
    node_kernel<36, 24><<<(NROIS * 24 + 255) / 256, 256, 0, stream>>>(h1, s2, cnt, root2, b2, h2);

    // Layer 3 (cin=24, cout=5)
    edge_kernel<24, 5, false><<<EB, 256, 0, stream>>>(ea, er, lw3, lb3, h2, s3, cnt);
    node_kernel<24, 5><<<(NROIS * 5 + 255) / 256, 256, 0, stream>>>(h2, s3, cnt, root3, b3, h3);

    // Pairwise L1 distance tail
    cbt_kernel<<<NROIS, 256, 0, stream>>>(h3, (float*)d_out);
}

// Round 2
// 307.557 us; speedup vs baseline: 4.4684x; 4.4684x over previous
//
#include <hip/hip_runtime.h>

#define NROIS 512
#define NEDGES 262144

// ---------------------------------------------------------------------------
// edge_index may arrive as int64 (reference dtype) or int32 (harness downcast).
// For int64 little-endian with values in [0,512), all odd 32-bit words of the
// first 64 elements are zero; for int32 they are random node ids (P(all 0)~0).
__device__ __forceinline__ int detect_i64(const unsigned* __restrict__ er) {
    unsigned acc = 0;
#pragma unroll
    for (int i = 0; i < 64; ++i) acc |= er[2 * i + 1];
    return acc == 0u;
}

__device__ __forceinline__ void load_edge(const unsigned* __restrict__ er,
                                          bool i64, int e, int& src, int& dst) {
    if (i64) { src = (int)er[2 * e]; dst = (int)er[2 * NEDGES + 2 * e]; }
    else     { src = (int)er[e];     dst = (int)er[NEDGES + e]; }
}

// ---------------------------------------------------------------------------
// prep: build padded weight tables lwT[r][8] = {lb[r], lw[0][r]..lw[5][r], 0}
// for all three layers, and zero the histogram counters. One block.
__global__ __launch_bounds__(256) void prep_kernel(
    const float* __restrict__ lw1, const float* __restrict__ lb1,
    const float* __restrict__ lw2, const float* __restrict__ lb2,
    const float* __restrict__ lw3, const float* __restrict__ lb3,
    float* __restrict__ lwT1, float* __restrict__ lwT2, float* __restrict__ lwT3,
    int* __restrict__ gcount)
{
    const int t = threadIdx.x;
    for (int r = t; r < 36; r += 256) {
        lwT1[r * 8] = lb1[r];
#pragma unroll
        for (int v = 0; v < 6; ++v) lwT1[r * 8 + 1 + v] = lw1[v * 36 + r];
        lwT1[r * 8 + 7] = 0.f;
    }
    for (int r = t; r < 864; r += 256) {
        lwT2[r * 8] = lb2[r];
#pragma unroll
        for (int v = 0; v < 6; ++v) lwT2[r * 8 + 1 + v] = lw2[v * 864 + r];
        lwT2[r * 8 + 7] = 0.f;
    }
    for (int r = t; r < 120; r += 256) {
        lwT3[r * 8] = lb3[r];
#pragma unroll
        for (int v = 0; v < 6; ++v) lwT3[r * 8 + 1 + v] = lw3[v * 120 + r];
        lwT3[r * 8 + 7] = 0.f;
    }
    for (int r = t; r < NROIS; r += 256) gcount[r] = 0;
}

// ---------------------------------------------------------------------------
// histogram of dst (per-block LDS hist, then one int atomic per bin per block)
__global__ __launch_bounds__(256) void hist_kernel(const unsigned* __restrict__ er,
                                                   int* __restrict__ gcount)
{
    __shared__ int lh[NROIS];
    __shared__ int s_l;
    if (threadIdx.x == 0) s_l = detect_i64(er);
    for (int i = threadIdx.x; i < NROIS; i += 256) lh[i] = 0;
    __syncthreads();
    const bool L = (s_l != 0);
    for (int e = blockIdx.x * 256 + threadIdx.x; e < NEDGES; e += 256 * 256) {
        int dst = L ? (int)er[2 * NEDGES + 2 * e] : (int)er[NEDGES + e];
        atomicAdd(&lh[dst], 1);
    }
    __syncthreads();
    for (int i = threadIdx.x; i < NROIS; i += 256)
        if (lh[i]) atomicAdd(&gcount[i], lh[i]);
}

// exclusive scan over 512 counters -> start[513]; cursor = start copy. 1 block.
__global__ __launch_bounds__(512) void scan_kernel(const int* __restrict__ gcount,
                                                   int* __restrict__ start,
                                                   int* __restrict__ cursor)
{
    __shared__ int tmp[NROIS];
    const int t = threadIdx.x;
    tmp[t] = gcount[t];
    __syncthreads();
    for (int off = 1; off < NROIS; off <<= 1) {
        int v = tmp[t];
        int add = (t >= off) ? tmp[t - off] : 0;
        __syncthreads();
        tmp[t] = v + add;
        __syncthreads();
    }
    start[t + 1] = tmp[t];               // inclusive -> start[t+1]
    if (t == 0) start[0] = 0;
    cursor[t] = (t == 0) ? 0 : tmp[t - 1];
}

// scatter edges into dst-bucketed order: perm_src[pos] = (e<<9)|src
__global__ __launch_bounds__(256) void scatter_kernel(const unsigned* __restrict__ er,
                                                      int* __restrict__ cursor,
                                                      unsigned* __restrict__ perm_src)
{
    __shared__ int s_l;
    if (threadIdx.x == 0) s_l = detect_i64(er);
    __syncthreads();
    const bool L = (s_l != 0);
    const int e = blockIdx.x * 256 + threadIdx.x;
    int src, dst;
    load_edge(er, L, e, src, dst);
    int pos = atomicAdd(&cursor[dst], 1);
    perm_src[pos] = ((unsigned)e << 9) | (unsigned)src;
}

// ---------------------------------------------------------------------------
// Fused per-dst aggregation + node update. Block b owns dst node b.
//   msg[o] = sum_edges  sum_i hin[src,i] * relu(lb[i,o] + sum_v a[v]*lw[v,i,o])
//   hout[b,o] = relu(msg[o]/max(cnt,1) + sum_k hin[b,k]*root[k,o] + bias[o])
template <int CIN, int COUT>
__global__ __launch_bounds__(256) void edge_aggr_kernel(
    const float* __restrict__ ea, const unsigned* __restrict__ perm_src,
    const int* __restrict__ start, const float* __restrict__ lwT,
    const float* __restrict__ hin, const float* __restrict__ root,
    const float* __restrict__ bias, float* __restrict__ hout)
{
    __shared__ float sred[4][COUT];
    const int b = blockIdx.x;
    const int s0 = start[b];
    const int cnt = start[b + 1] - s0;

    float macc[COUT];
#pragma unroll
    for (int o = 0; o < COUT; ++o) macc[o] = 0.f;

    for (int t = threadIdx.x; t < cnt; t += 256) {
        const unsigned ps = perm_src[s0 + t];
        const int e = (int)(ps >> 9);
        const int src = (int)(ps & 511u);
        const float2* eap = reinterpret_cast<const float2*>(ea + e * 6);
        const float2 a01 = eap[0], a23 = eap[1], a45 = eap[2];
        const float* __restrict__ hs = hin + src * CIN;
#pragma unroll 2
        for (int i = 0; i < CIN; ++i) {
            const float hi = hs[i];
            const float* __restrict__ w = lwT + (size_t)(i * COUT) * 8;
#pragma unroll
            for (int o = 0; o < COUT; ++o) {
                const float* __restrict__ w8 = w + o * 8;
                float tt = w8[0];
                tt = fmaf(a01.x, w8[1], tt);
                tt = fmaf(a01.y, w8[2], tt);
                tt = fmaf(a23.x, w8[3], tt);
                tt = fmaf(a23.y, w8[4], tt);
                tt = fmaf(a45.x, w8[5], tt);
                tt = fmaf(a45.y, w8[6], tt);
                macc[o] = fmaf(hi, fmaxf(tt, 0.f), macc[o]);
            }
        }
    }

    // wave reduce (64 lanes)
    const int lane = threadIdx.x & 63;
    const int wid = threadIdx.x >> 6;
#pragma unroll
    for (int d = 32; d > 0; d >>= 1) {
#pragma unroll
        for (int o = 0; o < COUT; ++o) macc[o] += __shfl_down(macc[o], d);
    }
    if (lane == 0) {
#pragma unroll
        for (int o = 0; o < COUT; ++o) sred[wid][o] = macc[o];
    }
    __syncthreads();

    const int o = threadIdx.x;
    if (o < COUT) {
        float tot = sred[0][o] + sred[1][o] + sred[2][o] + sred[3][o];
        float aggr = tot / fmaxf((float)cnt, 1.f);
        float r = bias[o];
        for (int k = 0; k < CIN; ++k)
            r = fmaf(hin[b * CIN + k], root[k * COUT + o], r);
        hout[b * COUT + o] = fmaxf(aggr + r, 0.f);
    }
}

// ---------------------------------------------------------------------------
// cbt[i,j] = sum_k |h[i,k]-h[j,k]|, h: [512,5] staged in LDS, block per row i
__global__ __launch_bounds__(256) void cbt_kernel(const float* __restrict__ h,
                                                  float* __restrict__ out)
{
    __shared__ float sh[NROIS * 5];
    for (int t = threadIdx.x; t < NROIS * 5; t += 256) sh[t] = h[t];
    __syncthreads();
    const int i = blockIdx.x;
    float hi[5];
#pragma unroll
    for (int k = 0; k < 5; ++k) hi[k] = sh[i * 5 + k];
    for (int j = threadIdx.x; j < NROIS; j += 256) {
        float s = 0.f;
#pragma unroll
        for (int k = 0; k < 5; ++k) s += fabsf(hi[k] - sh[j * 5 + k]);
        out[i * NROIS + j] = s;
    }
}

// ---------------------------------------------------------------------------
extern "C" void kernel_launch(void* const* d_in, const int* in_sizes, int n_in,
                              void* d_out, int out_size, void* d_ws, size_t ws_size,
                              hipStream_t stream)
{
    const float*    x     = (const float*)d_in[0];
    const float*    ea    = (const float*)d_in[1];
    const unsigned* er    = (const unsigned*)d_in[2];
    const float*    lw1   = (const float*)d_in[3];
    const float*    lb1   = (const float*)d_in[4];
    const float*    root1 = (const float*)d_in[5];
    const float*    b1    = (const float*)d_in[6];
    const float*    lw2   = (const float*)d_in[7];
    const float*    lb2   = (const float*)d_in[8];
    const float*    root2 = (const float*)d_in[9];
    const float*    b2    = (const float*)d_in[10];
    const float*    lw3   = (const float*)d_in[11];
    const float*    lb3   = (const float*)d_in[12];
    const float*    root3 = (const float*)d_in[13];
    const float*    b3    = (const float*)d_in[14];

    float* ws = (float*)d_ws;
    float* lwT1 = ws;                         // 36*8   = 288
    float* lwT2 = lwT1 + 288;                 // 864*8  = 6912
    float* lwT3 = lwT2 + 6912;                // 120*8  = 960
    float* h1   = lwT3 + 960;                 // 512*36 = 18432
    float* h2   = h1 + NROIS * 36;            // 512*24 = 12288
    float* h3   = h2 + NROIS * 24;            // 512*5  = 2560
    int*   gcount   = (int*)(h3 + NROIS * 5); // 512
    int*   start    = gcount + NROIS;         // 513
    int*   cursor   = start + NROIS + 1;      // 512
    unsigned* perm_src = (unsigned*)(cursor + NROIS); // 262144
    // total ~ 1.22 MB

    // --- prep + counting sort by dst (reused by all 3 layers) ---
    prep_kernel<<<1, 256, 0, stream>>>(lw1, lb1, lw2, lb2, lw3, lb3,
                                       lwT1, lwT2, lwT3, gcount);
    hist_kernel<<<256, 256, 0, stream>>>(er, gcount);
    scan_kernel<<<1, 512, 0, stream>>>(gcount, start, cursor);
    scatter_kernel<<<NEDGES / 256, 256, 0, stream>>>(er, cursor, perm_src);

    // --- three fused NNConv layers, one block per dst node ---
    edge_aggr_kernel<1, 36><<<NROIS, 256, 0, stream>>>(
        ea, perm_src, start, lwT1, x, root1, b1, h1);
    edge_aggr_kernel<36, 24><<<NROIS, 256, 0, stream>>>(
        ea, perm_src, start, lwT2, h1, root2, b2, h2);
    edge_aggr_kernel<24, 5><<<NROIS, 256, 0, stream>>>(
        ea, perm_src, start, lwT3, h2, root3, b3, h3);

    // --- pairwise L1 distance tail ---
    cbt_kernel<<<NROIS, 256, 0, stream>>>(h3, (float*)d_out);
}

// Round 3
// 164.422 us; speedup vs baseline: 8.3583x; 1.8705x over previous
//
#include <hip/hip_runtime.h>

#define NROIS 512
#define NEDGES 262144

// ---------------------------------------------------------------------------
// edge_index may arrive as int64 (reference dtype) or int32 (harness downcast).
__device__ __forceinline__ int detect_i64(const unsigned* __restrict__ er) {
    unsigned acc = 0;
#pragma unroll
    for (int i = 0; i < 64; ++i) acc |= er[2 * i + 1];
    return acc == 0u;
}

__device__ __forceinline__ void load_edge(const unsigned* __restrict__ er,
                                          bool i64, int e, int& src, int& dst) {
    if (i64) { src = (int)er[2 * e]; dst = (int)er[2 * NEDGES + 2 * e]; }
    else     { src = (int)er[e];     dst = (int)er[NEDGES + e]; }
}

__global__ __launch_bounds__(256) void zero_kernel(int* __restrict__ p, int n) {
    int t = blockIdx.x * 256 + threadIdx.x;
    if (t < n) p[t] = 0;
}

// histogram of dst (per-block LDS hist, then one int atomic per bin per block)
__global__ __launch_bounds__(256) void hist_kernel(const unsigned* __restrict__ er,
                                                   int* __restrict__ gcount)
{
    __shared__ int lh[NROIS];
    __shared__ int s_l;
    if (threadIdx.x == 0) s_l = detect_i64(er);
    for (int i = threadIdx.x; i < NROIS; i += 256) lh[i] = 0;
    __syncthreads();
    const bool L = (s_l != 0);
    for (int e = blockIdx.x * 256 + threadIdx.x; e < NEDGES; e += 256 * 256) {
        int dst = L ? (int)er[2 * NEDGES + 2 * e] : (int)er[NEDGES + e];
        atomicAdd(&lh[dst], 1);
    }
    __syncthreads();
    for (int i = threadIdx.x; i < NROIS; i += 256)
        if (lh[i]) atomicAdd(&gcount[i], lh[i]);
}

// exclusive scan over 512 counters -> start[513]; cursor = start copy. 1 block.
__global__ __launch_bounds__(512) void scan_kernel(const int* __restrict__ gcount,
                                                   int* __restrict__ start,
                                                   int* __restrict__ cursor)
{
    __shared__ int tmp[NROIS];
    const int t = threadIdx.x;
    tmp[t] = gcount[t];
    __syncthreads();
    for (int off = 1; off < NROIS; off <<= 1) {
        int v = tmp[t];
        int add = (t >= off) ? tmp[t - off] : 0;
        __syncthreads();
        tmp[t] = v + add;
        __syncthreads();
    }
    start[t + 1] = tmp[t];
    if (t == 0) start[0] = 0;
    cursor[t] = (t == 0) ? 0 : tmp[t - 1];
}

// scatter with per-block LDS bucketing: 64 blocks x 256 threads x 16 edges.
// Global atomics: one per (block,bin) for range reservation (~32K total).
__global__ __launch_bounds__(256) void scatter_kernel(const unsigned* __restrict__ er,
                                                      int* __restrict__ gcursor,
                                                      unsigned* __restrict__ perm)
{
    __shared__ int lh[NROIS];
    __shared__ int lbase[NROIS];
    __shared__ int s_l;
    const int t = threadIdx.x;
    if (t == 0) s_l = detect_i64(er);
    for (int i = t; i < NROIS; i += 256) lh[i] = 0;
    __syncthreads();
    const bool L = (s_l != 0);
    const int e0 = blockIdx.x * 4096;
#pragma unroll
    for (int k = 0; k < 16; ++k) {
        int e = e0 + k * 256 + t, src, dst;
        load_edge(er, L, e, src, dst);
        atomicAdd(&lh[dst], 1);
    }
    __syncthreads();
    for (int i = t; i < NROIS; i += 256) {
        int c = lh[i];
        lbase[i] = c ? atomicAdd(&gcursor[i], c) : 0;
    }
    __syncthreads();
#pragma unroll
    for (int k = 0; k < 16; ++k) {
        int e = e0 + k * 256 + t, src, dst;
        load_edge(er, L, e, src, dst);
        int pos = atomicAdd(&lbase[dst], 1);
        perm[pos] = ((unsigned)e << 9) | (unsigned)src;
    }
}

// gather edge_attr into sorted order, packed rows {a0..a5, ps, 0} (32B aligned)
__global__ __launch_bounds__(256) void pack_kernel(const float* __restrict__ ea,
                                                   const unsigned* __restrict__ perm,
                                                   float* __restrict__ eas)
{
    const int tid = blockIdx.x * 256 + threadIdx.x;
    const unsigned ps = perm[tid];
    const int e = (int)(ps >> 9);
    const float2* s = reinterpret_cast<const float2*>(ea + (size_t)e * 6);
    const float2 a0 = s[0], a1 = s[1], a2 = s[2];
    float4* d = reinterpret_cast<float4*>(eas + (size_t)tid * 8);
    d[0] = make_float4(a0.x, a0.y, a1.x, a1.y);
    d[1] = make_float4(a2.x, a2.y, __uint_as_float(ps), 0.f);
}

// ---------------------------------------------------------------------------
// Edge aggregation, weights-in-registers. Thread owns NP (i,o) pairs (single i),
// loops over a chunk of dst's edge list; cross-thread (i) reduction once at end.
//   grid = (SPLIT, NROIS); partial[chunk][dst][COUT]
template <int CIN, int COUT, int NP, int BLOCK, int SPLIT>
__global__ __launch_bounds__(BLOCK) void edge_aggr_kernel(
    const float* __restrict__ eas, const float* __restrict__ ea,
    const unsigned* __restrict__ perm, const int* __restrict__ start,
    const float* __restrict__ lw, const float* __restrict__ lb,
    const float* __restrict__ hin, float* __restrict__ partial, int packed)
{
    constexpr int OGRP = COUT / NP;       // o-groups per i
    constexpr int TUSED = CIN * OGRP;     // active threads
    const int t = threadIdx.x;
    const int tc = (t < TUSED) ? t : 0;   // clamp: idle lanes shadow thread 0
    const int ii = tc / OGRP, og = tc % OGRP;

    float wb[NP], wv[NP][6];
#pragma unroll
    for (int p = 0; p < NP; ++p) {
        const int o = og * NP + p;
        wb[p] = lb[ii * COUT + o];
#pragma unroll
        for (int v = 0; v < 6; ++v) wv[p][v] = lw[v * (CIN * COUT) + ii * COUT + o];
    }

    const int dst = blockIdx.y, chunk = blockIdx.x;
    const int s0 = start[dst];
    const int cnt = start[dst + 1] - s0;
    const int c0 = s0 + (cnt * chunk) / SPLIT;
    const int c1 = s0 + (cnt * (chunk + 1)) / SPLIT;

    float acc[NP];
#pragma unroll
    for (int p = 0; p < NP; ++p) acc[p] = 0.f;

#pragma unroll 4
    for (int idx = c0; idx < c1; ++idx) {
        float a0, a1, a2, a3, a4, a5;
        unsigned ps;
        if (packed) {          // uniform branch
            const float* __restrict__ ap = eas + (size_t)idx * 8;
            a0 = ap[0]; a1 = ap[1]; a2 = ap[2]; a3 = ap[3]; a4 = ap[4]; a5 = ap[5];
            ps = __float_as_uint(ap[6]);
        } else {
            ps = perm[idx];
            const float* __restrict__ ap = ea + (size_t)(ps >> 9) * 6;
            a0 = ap[0]; a1 = ap[1]; a2 = ap[2]; a3 = ap[3]; a4 = ap[4]; a5 = ap[5];
        }
        const int src = (int)(ps & 511u);
        const float hsv = hin[src * CIN + ii];
#pragma unroll
        for (int p = 0; p < NP; ++p) {
            float tt = wb[p];
            tt = fmaf(a0, wv[p][0], tt);
            tt = fmaf(a1, wv[p][1], tt);
            tt = fmaf(a2, wv[p][2], tt);
            tt = fmaf(a3, wv[p][3], tt);
            tt = fmaf(a4, wv[p][4], tt);
            tt = fmaf(a5, wv[p][5], tt);
            acc[p] = fmaf(hsv, fmaxf(tt, 0.f), acc[p]);
        }
    }

    float* __restrict__ out = partial + ((size_t)chunk * NROIS + dst) * COUT;
    if constexpr (CIN == 1) {
        if (t < COUT) out[t] = acc[0];    // NP==1, o==t, no cross-i reduction
    } else {
        __shared__ float red[CIN * COUT];
        if (t < TUSED) {
#pragma unroll
            for (int p = 0; p < NP; ++p) red[ii * COUT + og * NP + p] = acc[p];
        }
        __syncthreads();
        if (t < COUT) {
            float tot = 0.f;
#pragma unroll 4
            for (int k = 0; k < CIN; ++k) tot += red[k * COUT + t];
            out[t] = tot;
        }
    }
}

// combine chunks + mean + root term + bias + relu
template <int CIN, int COUT, int SPLIT>
__global__ __launch_bounds__(256) void node_kernel(
    const float* __restrict__ hin, const float* __restrict__ partial,
    const int* __restrict__ start, const float* __restrict__ root,
    const float* __restrict__ bias, float* __restrict__ hout)
{
    int t = blockIdx.x * 256 + threadIdx.x;
    if (t >= NROIS * COUT) return;
    int i = t / COUT, o = t - i * COUT;
    float s = 0.f;
#pragma unroll
    for (int c = 0; c < SPLIT; ++c) s += partial[((size_t)c * NROIS + i) * COUT + o];
    int cnt = start[i + 1] - start[i];
    float aggr = s / fmaxf((float)cnt, 1.f);
    float r = bias[o];
#pragma unroll 4
    for (int k = 0; k < CIN; ++k) r = fmaf(hin[i * CIN + k], root[k * COUT + o], r);
    hout[t] = fmaxf(aggr + r, 0.f);
}

// cbt[i,j] = sum_k |h[i,k]-h[j,k]|, h: [512,5] staged in LDS, block per row i
__global__ __launch_bounds__(256) void cbt_kernel(const float* __restrict__ h,
                                                  float* __restrict__ out)
{
    __shared__ float sh[NROIS * 5];
    for (int t = threadIdx.x; t < NROIS * 5; t += 256) sh[t] = h[t];
    __syncthreads();
    const int i = blockIdx.x;
    float hi[5];
#pragma unroll
    for (int k = 0; k < 5; ++k) hi[k] = sh[i * 5 + k];
    for (int j = threadIdx.x; j < NROIS; j += 256) {
        float s = 0.f;
#pragma unroll
        for (int k = 0; k < 5; ++k) s += fabsf(hi[k] - sh[j * 5 + k]);
        out[i * NROIS + j] = s;
    }
}

// ---------------------------------------------------------------------------
extern "C" void kernel_launch(void* const* d_in, const int* in_sizes, int n_in,
                              void* d_out, int out_size, void* d_ws, size_t ws_size,
                              hipStream_t stream)
{
    const float*    x     = (const float*)d_in[0];
    const float*    ea    = (const float*)d_in[1];
    const unsigned* er    = (const unsigned*)d_in[2];
    const float*    lw1   = (const float*)d_in[3];
    const float*    lb1   = (const float*)d_in[4];
    const float*    root1 = (const float*)d_in[5];
    const float*    b1    = (const float*)d_in[6];
    const float*    lw2   = (const float*)d_in[7];
    const float*    lb2   = (const float*)d_in[8];
    const float*    root2 = (const float*)d_in[9];
    const float*    b2    = (const float*)d_in[10];
    const float*    lw3   = (const float*)d_in[11];
    const float*    lb3   = (const float*)d_in[12];
    const float*    root3 = (const float*)d_in[13];
    const float*    b3    = (const float*)d_in[14];

    const size_t easN = (size_t)NEDGES * 8;            // floats
    const size_t restN = 18432 + 12288 + 2560 + 147456; // h1,h2,h3,partial
    const size_t intN = 512 + 513 + 512 + NEDGES;
    const size_t needPacked = (easN + restN + intN) * 4;
    const int packed = (ws_size >= needPacked) ? 1 : 0;

    float* ws   = (float*)d_ws;
    float* eas  = ws;                                  // 8MB (packed mode only)
    float* rest = packed ? (ws + easN) : ws;
    float* h1   = rest;                 // 512*36
    float* h2   = h1 + NROIS * 36;      // 512*24
    float* h3   = h2 + NROIS * 24;      // 512*5
    float* part = h3 + NROIS * 5;       // 147456 (max over layers, reused)
    int* gcount = (int*)(part + 147456);
    int* start  = gcount + NROIS;       // 513
    int* cursor = start + NROIS + 1;    // 512
    unsigned* perm = (unsigned*)(cursor + NROIS);      // 262144

    // --- counting sort by dst + packed edge rows (reused by all 3 layers) ---
    zero_kernel<<<2, 256, 0, stream>>>(gcount, NROIS);
    hist_kernel<<<256, 256, 0, stream>>>(er, gcount);
    scan_kernel<<<1, 512, 0, stream>>>(gcount, start, cursor);
    scatter_kernel<<<NEDGES / 4096, 256, 0, stream>>>(er, cursor, perm);
    if (packed)
        pack_kernel<<<NEDGES / 256, 256, 0, stream>>>(ea, perm, eas);

    // --- layer 1: cin=1, cout=36, NP=1 (36 lanes), SPLIT=8 ---
    edge_aggr_kernel<1, 36, 1, 64, 8><<<dim3(8, NROIS), 64, 0, stream>>>(
        eas, ea, perm, start, lw1, lb1, x, part, packed);
    node_kernel<1, 36, 8><<<(NROIS * 36 + 255) / 256, 256, 0, stream>>>(
        x, part, start, root1, b1, h1);

    // --- layer 2: cin=36, cout=24, NP=4 (216 threads), SPLIT=4 ---
    edge_aggr_kernel<36, 24, 4, 256, 4><<<dim3(4, NROIS), 256, 0, stream>>>(
        eas, ea, perm, start, lw2, lb2, h1, part, packed);
    node_kernel<36, 24, 4><<<(NROIS * 24 + 255) / 256, 256, 0, stream>>>(
        h1, part, start, root2, b2, h2);

    // --- layer 3: cin=24, cout=5, NP=1 (120 threads), SPLIT=4 ---
    edge_aggr_kernel<24, 5, 1, 128, 4><<<dim3(4, NROIS), 128, 0, stream>>>(
        eas, ea, perm, start, lw3, lb3, h2, part, packed);
    node_kernel<24, 5, 4><<<(NROIS * 5 + 255) / 256, 256, 0, stream>>>(
        h2, part, start, root3, b3, h3);

    // --- pairwise L1 distance tail ---
    cbt_kernel<<<NROIS, 256, 0, stream>>>(h3, (float*)d_out);
}

// Round 4
// 139.670 us; speedup vs baseline: 9.8395x; 1.1772x over previous
//
#include <hip/hip_runtime.h>

#define NROIS 512
#define NEDGES 262144

// ---------------------------------------------------------------------------
// edge_index may arrive as int64 (reference dtype) or int32 (harness downcast).
__device__ __forceinline__ int detect_i64(const unsigned* __restrict__ er) {
    unsigned acc = 0;
#pragma unroll
    for (int i = 0; i < 64; ++i) acc |= er[2 * i + 1];
    return acc == 0u;
}

__device__ __forceinline__ void load_edge(const unsigned* __restrict__ er,
                                          bool i64, int e, int& src, int& dst) {
    if (i64) { src = (int)er[2 * e]; dst = (int)er[2 * NEDGES + 2 * e]; }
    else     { src = (int)er[e];     dst = (int)er[NEDGES + e]; }
}

// ---------------------------------------------------------------------------
// hist: 64 blocks x 4096 edges, per-block LDS hist -> gpart[64][512] (no atomics
// on global, no zero pass needed)
__global__ __launch_bounds__(256) void hist_kernel(const unsigned* __restrict__ er,
                                                   int* __restrict__ gpart)
{
    __shared__ int lh[NROIS];
    __shared__ int s_l;
    const int t = threadIdx.x;
    if (t == 0) s_l = detect_i64(er);
    for (int i = t; i < NROIS; i += 256) lh[i] = 0;
    __syncthreads();
    const bool L = (s_l != 0);
    const int e0 = blockIdx.x * 4096;
#pragma unroll
    for (int k = 0; k < 16; ++k) {
        int e = e0 + k * 256 + t, src, dst;
        load_edge(er, L, e, src, dst);
        atomicAdd(&lh[dst], 1);
    }
    __syncthreads();
    for (int i = t; i < NROIS; i += 256) gpart[blockIdx.x * NROIS + i] = lh[i];
}

// scan: sum 64 partials per bin, inclusive scan -> start[513], cursor (exclusive)
__global__ __launch_bounds__(512) void scan_kernel(const int* __restrict__ gpart,
                                                   int* __restrict__ start,
                                                   int* __restrict__ cursor)
{
    __shared__ int tmp[NROIS];
    const int t = threadIdx.x;
    int own = 0;
#pragma unroll 8
    for (int b = 0; b < 64; ++b) own += gpart[b * NROIS + t];
    tmp[t] = own;
    __syncthreads();
    for (int off = 1; off < NROIS; off <<= 1) {
        int v = tmp[t];
        int add = (t >= off) ? tmp[t - off] : 0;
        __syncthreads();
        tmp[t] = v + add;
        __syncthreads();
    }
    start[t + 1] = tmp[t];
    if (t == 0) start[0] = 0;
    cursor[t] = tmp[t] - own;            // exclusive prefix
}

// scatter + fused pack: 256 blocks x 1024 edges. Per-block LDS bucketing, one
// global atomic per (block,bin). Writes perm and (if packed) eas rows directly.
__global__ __launch_bounds__(256) void scatter_kernel(const unsigned* __restrict__ er,
                                                      const float* __restrict__ ea,
                                                      int* __restrict__ gcursor,
                                                      unsigned* __restrict__ perm,
                                                      float* __restrict__ eas,
                                                      int packed)
{
    __shared__ int lh[NROIS];
    __shared__ int lbase[NROIS];
    __shared__ int s_l;
    const int t = threadIdx.x;
    if (t == 0) s_l = detect_i64(er);
    for (int i = t; i < NROIS; i += 256) lh[i] = 0;
    __syncthreads();
    const bool L = (s_l != 0);
    const int e0 = blockIdx.x * 1024;
#pragma unroll
    for (int k = 0; k < 4; ++k) {
        int e = e0 + k * 256 + t, src, dst;
        load_edge(er, L, e, src, dst);
        atomicAdd(&lh[dst], 1);
    }
    __syncthreads();
    for (int i = t; i < NROIS; i += 256) {
        int c = lh[i];
        lbase[i] = c ? atomicAdd(&gcursor[i], c) : 0;
    }
    __syncthreads();
#pragma unroll
    for (int k = 0; k < 4; ++k) {
        int e = e0 + k * 256 + t, src, dst;
        load_edge(er, L, e, src, dst);
        int pos = atomicAdd(&lbase[dst], 1);
        unsigned ps = ((unsigned)e << 9) | (unsigned)src;
        perm[pos] = ps;
        if (packed) {
            const float2* s = reinterpret_cast<const float2*>(ea + (size_t)e * 6);
            const float2 a0 = s[0], a1 = s[1], a2 = s[2];
            float4* d = reinterpret_cast<float4*>(eas + (size_t)pos * 8);
            d[0] = make_float4(a0.x, a0.y, a1.x, a1.y);
            d[1] = make_float4(a2.x, a2.y, __uint_as_float(ps), 0.f);
        }
    }
}

// ---------------------------------------------------------------------------
// Edge aggregation, weights-in-registers. Thread owns NP (i,o) pairs (single i,
// NP consecutive-by-group o's), loops over a chunk of dst's sorted edge list;
// cross-thread (i) reduction once per block at the end.
//   grid = (SPLIT, NROIS); partial[chunk][dst][COUT]
template <int CIN, int COUT, int NP, int BLOCK, int SPLIT, bool PACKED>
__global__ __launch_bounds__(BLOCK) void edge_aggr_kernel(
    const float* __restrict__ eas, const float* __restrict__ ea,
    const unsigned* __restrict__ perm, const int* __restrict__ start,
    const float* __restrict__ lw, const float* __restrict__ lb,
    const float* __restrict__ hin, float* __restrict__ partial)
{
    constexpr int OGRP = COUT / NP;       // o-groups per i
    constexpr int TUSED = CIN * OGRP;     // active threads
    const int t = threadIdx.x;
    const int tc = (t < TUSED) ? t : 0;   // clamp: idle lanes shadow thread 0
    const int ii = tc / OGRP, og = tc % OGRP;

    float wb[NP], wv[NP][6];
#pragma unroll
    for (int p = 0; p < NP; ++p) {
        const int o = og * NP + p;
        wb[p] = lb[ii * COUT + o];
#pragma unroll
        for (int v = 0; v < 6; ++v) wv[p][v] = lw[v * (CIN * COUT) + ii * COUT + o];
    }

    const int dst = blockIdx.y, chunk = blockIdx.x;
    const int s0 = start[dst];
    const int cnt = start[dst + 1] - s0;
    const int c0 = s0 + (cnt * chunk) / SPLIT;
    const int c1 = s0 + (cnt * (chunk + 1)) / SPLIT;

    float acc[NP];
#pragma unroll
    for (int p = 0; p < NP; ++p) acc[p] = 0.f;

#pragma unroll 4
    for (int idx = c0; idx < c1; ++idx) {
        float a0, a1, a2, a3, a4, a5;
        unsigned ps;
        if constexpr (PACKED) {
            const float* __restrict__ ap = eas + (size_t)idx * 8;
            a0 = ap[0]; a1 = ap[1]; a2 = ap[2]; a3 = ap[3]; a4 = ap[4]; a5 = ap[5];
            ps = __float_as_uint(ap[6]);
        } else {
            ps = perm[idx];
            const float* __restrict__ ap = ea + (size_t)(ps >> 9) * 6;
            a0 = ap[0]; a1 = ap[1]; a2 = ap[2]; a3 = ap[3]; a4 = ap[4]; a5 = ap[5];
        }
        const int src = (int)(ps & 511u);
        const float hsv = hin[src * CIN + ii];
#pragma unroll
        for (int p = 0; p < NP; ++p) {
            float tt = wb[p];
            tt = fmaf(a0, wv[p][0], tt);
            tt = fmaf(a1, wv[p][1], tt);
            tt = fmaf(a2, wv[p][2], tt);
            tt = fmaf(a3, wv[p][3], tt);
            tt = fmaf(a4, wv[p][4], tt);
            tt = fmaf(a5, wv[p][5], tt);
            acc[p] = fmaf(hsv, fmaxf(tt, 0.f), acc[p]);
        }
    }

    float* __restrict__ out = partial + ((size_t)chunk * NROIS + dst) * COUT;
    if constexpr (CIN == 1) {
        if (t < COUT) out[t] = acc[0];    // NP==1, o==t, no cross-i reduction
    } else {
        __shared__ float red[CIN * COUT];
        if (t < TUSED) {
#pragma unroll
            for (int p = 0; p < NP; ++p) red[ii * COUT + og * NP + p] = acc[p];
        }
        __syncthreads();
        if (t < COUT) {
            float tot = 0.f;
#pragma unroll 4
            for (int k = 0; k < CIN; ++k) tot += red[k * COUT + t];
            out[t] = tot;
        }
    }
}

// combine chunks + mean + root term + bias + relu
template <int CIN, int COUT, int SPLIT>
__global__ __launch_bounds__(256) void node_kernel(
    const float* __restrict__ hin, const float* __restrict__ partial,
    const int* __restrict__ start, const float* __restrict__ root,
    const float* __restrict__ bias, float* __restrict__ hout)
{
    int t = blockIdx.x * 256 + threadIdx.x;
    if (t >= NROIS * COUT) return;
    int i = t / COUT, o = t - i * COUT;
    float s = 0.f;
#pragma unroll
    for (int c = 0; c < SPLIT; ++c) s += partial[((size_t)c * NROIS + i) * COUT + o];
    int cnt = start[i + 1] - start[i];
    float aggr = s / fmaxf((float)cnt, 1.f);
    float r = bias[o];
#pragma unroll 4
    for (int k = 0; k < CIN; ++k) r = fmaf(hin[i * CIN + k], root[k * COUT + o], r);
    hout[t] = fmaxf(aggr + r, 0.f);
}

// cbt[i,j] = sum_k |h[i,k]-h[j,k]|, h: [512,5] staged in LDS, block per row i
__global__ __launch_bounds__(256) void cbt_kernel(const float* __restrict__ h,
                                                  float* __restrict__ out)
{
    __shared__ float sh[NROIS * 5];
    for (int t = threadIdx.x; t < NROIS * 5; t += 256) sh[t] = h[t];
    __syncthreads();
    const int i = blockIdx.x;
    float hi[5];
#pragma unroll
    for (int k = 0; k < 5; ++k) hi[k] = sh[i * 5 + k];
    for (int j = threadIdx.x; j < NROIS; j += 256) {
        float s = 0.f;
#pragma unroll
        for (int k = 0; k < 5; ++k) s += fabsf(hi[k] - sh[j * 5 + k]);
        out[i * NROIS + j] = s;
    }
}

// ---------------------------------------------------------------------------
extern "C" void kernel_launch(void* const* d_in, const int* in_sizes, int n_in,
                              void* d_out, int out_size, void* d_ws, size_t ws_size,
                              hipStream_t stream)
{
    const float*    x     = (const float*)d_in[0];
    const float*    ea    = (const float*)d_in[1];
    const unsigned* er    = (const unsigned*)d_in[2];
    const float*    lw1   = (const float*)d_in[3];
    const float*    lb1   = (const float*)d_in[4];
    const float*    root1 = (const float*)d_in[5];
    const float*    b1    = (const float*)d_in[6];
    const float*    lw2   = (const float*)d_in[7];
    const float*    lb2   = (const float*)d_in[8];
    const float*    root2 = (const float*)d_in[9];
    const float*    b2    = (const float*)d_in[10];
    const float*    lw3   = (const float*)d_in[11];
    const float*    lb3   = (const float*)d_in[12];
    const float*    root3 = (const float*)d_in[13];
    const float*    b3    = (const float*)d_in[14];

    const size_t easN  = (size_t)NEDGES * 8;                 // floats
    const size_t restN = 18432 + 12288 + 2560 + 147456 + 513 + 512 + NEDGES;
    const size_t needPacked = (easN + restN) * 4;
    const int packed = (ws_size >= needPacked) ? 1 : 0;

    float* ws   = (float*)d_ws;
    float* eas  = ws;                                  // 8 MB (packed mode only)
    float* rest = packed ? (ws + easN) : ws;
    float* h1   = rest;                 // 512*36
    float* h2   = h1 + NROIS * 36;      // 512*24
    float* h3   = h2 + NROIS * 24;      // 512*5
    float* part = h3 + NROIS * 5;       // 147456 floats (also gpart scratch)
    int* gpart  = (int*)part;           // 64*512 ints, used before layers
    int* start  = (int*)(part + 147456);
    int* cursor = start + NROIS + 1;    // 512
    unsigned* perm = (unsigned*)(cursor + NROIS);      // 262144

    // --- counting sort by dst + fused edge-attr pack (reused by all layers) ---
    hist_kernel<<<NEDGES / 4096, 256, 0, stream>>>(er, gpart);
    scan_kernel<<<1, 512, 0, stream>>>(gpart, start, cursor);
    scatter_kernel<<<NEDGES / 1024, 256, 0, stream>>>(er, ea, cursor, perm, eas, packed);

    if (packed) {
        edge_aggr_kernel<1, 36, 1, 64, 8, true><<<dim3(8, NROIS), 64, 0, stream>>>(
            eas, ea, perm, start, lw1, lb1, x, part);
        node_kernel<1, 36, 8><<<(NROIS * 36 + 255) / 256, 256, 0, stream>>>(
            x, part, start, root1, b1, h1);
        edge_aggr_kernel<36, 24, 8, 128, 8, true><<<dim3(8, NROIS), 128, 0, stream>>>(
            eas, ea, perm, start, lw2, lb2, h1, part);
        node_kernel<36, 24, 8><<<(NROIS * 24 + 255) / 256, 256, 0, stream>>>(
            h1, part, start, root2, b2, h2);
        edge_aggr_kernel<24, 5, 1, 128, 8, true><<<dim3(8, NROIS), 128, 0, stream>>>(
            eas, ea, perm, start, lw3, lb3, h2, part);
        node_kernel<24, 5, 8><<<(NROIS * 5 + 255) / 256, 256, 0, stream>>>(
            h2, part, start, root3, b3, h3);
    } else {
        edge_aggr_kernel<1, 36, 1, 64, 8, false><<<dim3(8, NROIS), 64, 0, stream>>>(
            eas, ea, perm, start, lw1, lb1, x, part);
        node_kernel<1, 36, 8><<<(NROIS * 36 + 255) / 256, 256, 0, stream>>>(
            x, part, start, root1, b1, h1);
        edge_aggr_kernel<36, 24, 8, 128, 8, false><<<dim3(8, NROIS), 128, 0, stream>>>(
            eas, ea, perm, start, lw2, lb2, h1, part);
        node_kernel<36, 24, 8><<<(NROIS * 24 + 255) / 256, 256, 0, stream>>>(
            h1, part, start, root2, b2, h2);
        edge_aggr_kernel<24, 5, 1, 128, 8, false><<<dim3(8, NROIS), 128, 0, stream>>>(
            eas, ea, perm, start, lw3, lb3, h2, part);
        node_kernel<24, 5, 8><<<(NROIS * 5 + 255) / 256, 256, 0, stream>>>(
            h2, part, start, root3, b3, h3);
    }

    // --- pairwise L1 distance tail ---
    cbt_kernel<<<NROIS, 256, 0, stream>>>(h3, (float*)d_out);
}

// Round 5
// 139.403 us; speedup vs baseline: 9.8584x; 1.0019x over previous
//
#include <hip/hip_runtime.h>

#define NROIS 512
#define NEDGES 262144

// ---------------------------------------------------------------------------
// edge_index may arrive as int64 (reference dtype) or int32 (harness downcast).
__device__ __forceinline__ int detect_i64(const unsigned* __restrict__ er) {
    unsigned acc = 0;
#pragma unroll
    for (int i = 0; i < 64; ++i) acc |= er[2 * i + 1];
    return acc == 0u;
}

__device__ __forceinline__ void load_edge(const unsigned* __restrict__ er,
                                          bool i64, int e, int& src, int& dst) {
    if (i64) { src = (int)er[2 * e]; dst = (int)er[2 * NEDGES + 2 * e]; }
    else     { src = (int)er[e];     dst = (int)er[NEDGES + e]; }
}

// ---------------------------------------------------------------------------
// hist: 256 blocks x 1024 edges, per-block LDS hist -> gpart[256][512]
__global__ __launch_bounds__(256) void hist_kernel(const unsigned* __restrict__ er,
                                                   int* __restrict__ gpart)
{
    __shared__ int lh[NROIS];
    __shared__ int s_l;
    const int t = threadIdx.x;
    if (t == 0) s_l = detect_i64(er);
    for (int i = t; i < NROIS; i += 256) lh[i] = 0;
    __syncthreads();
    const bool L = (s_l != 0);
    const int e0 = blockIdx.x * 1024;
#pragma unroll
    for (int k = 0; k < 4; ++k) {
        int e = e0 + k * 256 + t, src, dst;
        load_edge(er, L, e, src, dst);
        atomicAdd(&lh[dst], 1);
    }
    __syncthreads();
    for (int i = t; i < NROIS; i += 256) gpart[blockIdx.x * NROIS + i] = lh[i];
}

// scan: sum 256 partials per bin, inclusive scan -> start[513], cursor (exclusive)
__global__ __launch_bounds__(512) void scan_kernel(const int* __restrict__ gpart,
                                                   int* __restrict__ start,
                                                   int* __restrict__ cursor)
{
    __shared__ int tmp[NROIS];
    const int t = threadIdx.x;
    int own = 0;
#pragma unroll 8
    for (int b = 0; b < 256; ++b) own += gpart[b * NROIS + t];
    tmp[t] = own;
    __syncthreads();
    for (int off = 1; off < NROIS; off <<= 1) {
        int v = tmp[t];
        int add = (t >= off) ? tmp[t - off] : 0;
        __syncthreads();
        tmp[t] = v + add;
        __syncthreads();
    }
    start[t + 1] = tmp[t];
    if (t == 0) start[0] = 0;
    cursor[t] = tmp[t] - own;            // exclusive prefix
}

// scatter + fused pack: 256 blocks x 1024 edges. Per-block LDS bucketing, one
// global atomic per (block,bin). Writes perm and (if packed) eas rows directly.
__global__ __launch_bounds__(256) void scatter_kernel(const unsigned* __restrict__ er,
                                                      const float* __restrict__ ea,
                                                      int* __restrict__ gcursor,
                                                      unsigned* __restrict__ perm,
                                                      float* __restrict__ eas,
                                                      int packed)
{
    __shared__ int lh[NROIS];
    __shared__ int lbase[NROIS];
    __shared__ int s_l;
    const int t = threadIdx.x;
    if (t == 0) s_l = detect_i64(er);
    for (int i = t; i < NROIS; i += 256) lh[i] = 0;
    __syncthreads();
    const bool L = (s_l != 0);
    const int e0 = blockIdx.x * 1024;
#pragma unroll
    for (int k = 0; k < 4; ++k) {
        int e = e0 + k * 256 + t, src, dst;
        load_edge(er, L, e, src, dst);
        atomicAdd(&lh[dst], 1);
    }
    __syncthreads();
    for (int i = t; i < NROIS; i += 256) {
        int c = lh[i];
        lbase[i] = c ? atomicAdd(&gcursor[i], c) : 0;
    }
    __syncthreads();
#pragma unroll
    for (int k = 0; k < 4; ++k) {
        int e = e0 + k * 256 + t, src, dst;
        load_edge(er, L, e, src, dst);
        int pos = atomicAdd(&lbase[dst], 1);
        unsigned ps = ((unsigned)e << 9) | (unsigned)src;
        perm[pos] = ps;
        if (packed) {
            const float2* s = reinterpret_cast<const float2*>(ea + (size_t)e * 6);
            const float2 a0 = s[0], a1 = s[1], a2 = s[2];
            float4* d = reinterpret_cast<float4*>(eas + (size_t)pos * 8);
            d[0] = make_float4(a0.x, a0.y, a1.x, a1.y);
            d[1] = make_float4(a2.x, a2.y, __uint_as_float(ps), 0.f);
        }
    }
}

// ---------------------------------------------------------------------------
// per-edge attr fetch (packed rows of 8 floats, or fallback via perm+ea)
template <bool PACKED>
__device__ __forceinline__ void fetch_edge(const float* __restrict__ eas,
                                           const float* __restrict__ ea,
                                           const unsigned* __restrict__ perm,
                                           int idx, float a[6], unsigned& ps)
{
    if constexpr (PACKED) {
        const float4* ap4 = reinterpret_cast<const float4*>(eas + (size_t)idx * 8);
        const float4 r0 = ap4[0], r1 = ap4[1];
        a[0] = r0.x; a[1] = r0.y; a[2] = r0.z; a[3] = r0.w;
        a[4] = r1.x; a[5] = r1.y; ps = __float_as_uint(r1.z);
    } else {
        ps = perm[idx];
        const float* ap = ea + (size_t)(ps >> 9) * 6;
        a[0] = ap[0]; a[1] = ap[1]; a[2] = ap[2];
        a[3] = ap[3]; a[4] = ap[4]; a[5] = ap[5];
    }
}

__device__ __forceinline__ float edge_w(const float a[6], float wb, const float wv[6]) {
    float tt = wb;
    tt = fmaf(a[0], wv[0], tt);
    tt = fmaf(a[1], wv[1], tt);
    tt = fmaf(a[2], wv[2], tt);
    tt = fmaf(a[3], wv[3], tt);
    tt = fmaf(a[4], wv[4], tt);
    tt = fmaf(a[5], wv[5], tt);
    return fmaxf(tt, 0.f);
}

// ---------------------------------------------------------------------------
// Layer-2 style: thread owns (i, NP o's); weights in registers; loops a chunk
// of dst's sorted edge list. grid = (SPLIT, NROIS); partial[chunk][dst][COUT]
template <int CIN, int COUT, int NP, int BLOCK, int SPLIT, bool PACKED>
__global__ __launch_bounds__(BLOCK, 4) void edge_aggr_kernel(
    const float* __restrict__ eas, const float* __restrict__ ea,
    const unsigned* __restrict__ perm, const int* __restrict__ start,
    const float* __restrict__ lw, const float* __restrict__ lb,
    const float* __restrict__ hin, float* __restrict__ partial)
{
    constexpr int OGRP = COUT / NP;       // o-groups per i
    constexpr int TUSED = CIN * OGRP;     // active threads
    const int t = threadIdx.x;
    const int tc = (t < TUSED) ? t : 0;   // clamp: idle lanes shadow thread 0
    const int ii = tc / OGRP, og = tc % OGRP;

    float wb[NP], wv[NP][6];
#pragma unroll
    for (int p = 0; p < NP; ++p) {
        const int o = og * NP + p;
        wb[p] = lb[ii * COUT + o];
#pragma unroll
        for (int v = 0; v < 6; ++v) wv[p][v] = lw[v * (CIN * COUT) + ii * COUT + o];
    }

    const int dst = blockIdx.y, chunk = blockIdx.x;
    const int s0 = start[dst];
    const int cnt = start[dst + 1] - s0;
    const int c0 = s0 + (cnt * chunk) / SPLIT;
    const int c1 = s0 + (cnt * (chunk + 1)) / SPLIT;

    float acc[NP];
#pragma unroll
    for (int p = 0; p < NP; ++p) acc[p] = 0.f;

#pragma unroll 2
    for (int idx = c0; idx < c1; ++idx) {
        float a[6]; unsigned ps;
        fetch_edge<PACKED>(eas, ea, perm, idx, a, ps);
        const int src = (int)(ps & 511u);
        const float hsv = hin[src * CIN + ii];
#pragma unroll
        for (int p = 0; p < NP; ++p)
            acc[p] = fmaf(hsv, edge_w(a, wb[p], wv[p]), acc[p]);
    }

    __shared__ float red[CIN * COUT];
    if (t < TUSED) {
#pragma unroll
        for (int p = 0; p < NP; ++p) red[ii * COUT + og * NP + p] = acc[p];
    }
    __syncthreads();
    float* __restrict__ out = partial + ((size_t)chunk * NROIS + dst) * COUT;
    if (t < COUT) {
        float tot = 0.f;
#pragma unroll 4
        for (int k = 0; k < CIN; ++k) tot += red[k * COUT + t];
        out[t] = tot;
    }
}

// Layer-1 style (CIN==1): G edge-groups x COUT o's. Group g walks edges
// c0+g, c0+g+G, ... so lanes stay busy and loads pipeline.
template <int COUT, int G, int BLOCK, int SPLIT, bool PACKED>
__global__ __launch_bounds__(BLOCK, 4) void edge_aggr1_kernel(
    const float* __restrict__ eas, const float* __restrict__ ea,
    const unsigned* __restrict__ perm, const int* __restrict__ start,
    const float* __restrict__ lw, const float* __restrict__ lb,
    const float* __restrict__ hin, float* __restrict__ partial)
{
    constexpr int TUSED = G * COUT;
    const int t = threadIdx.x;
    const int tc = (t < TUSED) ? t : 0;
    const int g = tc / COUT, o = tc % COUT;

    float wb = lb[o], wv[6];
#pragma unroll
    for (int v = 0; v < 6; ++v) wv[v] = lw[v * COUT + o];

    const int dst = blockIdx.y, chunk = blockIdx.x;
    const int s0 = start[dst];
    const int cnt = start[dst + 1] - s0;
    const int c0 = s0 + (cnt * chunk) / SPLIT;
    const int c1 = s0 + (cnt * (chunk + 1)) / SPLIT;

    float acc = 0.f;
#pragma unroll 2
    for (int idx = c0 + g; idx < c1; idx += G) {
        float a[6]; unsigned ps;
        fetch_edge<PACKED>(eas, ea, perm, idx, a, ps);
        const float hsv = hin[(int)(ps & 511u)];
        acc = fmaf(hsv, edge_w(a, wb, wv), acc);
    }

    __shared__ float red[TUSED];
    if (t < TUSED) red[t] = acc;
    __syncthreads();
    float* __restrict__ out = partial + ((size_t)chunk * NROIS + dst) * COUT;
    if (t < COUT) {
        float tot = 0.f;
#pragma unroll
        for (int k = 0; k < G; ++k) tot += red[k * COUT + t];
        out[t] = tot;
    }
}

// Layer-3 style: G edge-groups x CIN i's, thread owns all COUT o's for its i.
template <int CIN, int COUT, int G, int BLOCK, int SPLIT, bool PACKED>
__global__ __launch_bounds__(BLOCK, 4) void edge_aggr3_kernel(
    const float* __restrict__ eas, const float* __restrict__ ea,
    const unsigned* __restrict__ perm, const int* __restrict__ start,
    const float* __restrict__ lw, const float* __restrict__ lb,
    const float* __restrict__ hin, float* __restrict__ partial)
{
    constexpr int TUSED = G * CIN;
    const int t = threadIdx.x;
    const int tc = (t < TUSED) ? t : 0;
    const int g = tc / CIN, ii = tc % CIN;

    float wb[COUT], wv[COUT][6];
#pragma unroll
    for (int o = 0; o < COUT; ++o) {
        wb[o] = lb[ii * COUT + o];
#pragma unroll
        for (int v = 0; v < 6; ++v) wv[o][v] = lw[v * (CIN * COUT) + ii * COUT + o];
    }

    const int dst = blockIdx.y, chunk = blockIdx.x;
    const int s0 = start[dst];
    const int cnt = start[dst + 1] - s0;
    const int c0 = s0 + (cnt * chunk) / SPLIT;
    const int c1 = s0 + (cnt * (chunk + 1)) / SPLIT;

    float acc[COUT];
#pragma unroll
    for (int o = 0; o < COUT; ++o) acc[o] = 0.f;

#pragma unroll 2
    for (int idx = c0 + g; idx < c1; idx += G) {
        float a[6]; unsigned ps;
        fetch_edge<PACKED>(eas, ea, perm, idx, a, ps);
        const float hsv = hin[(int)(ps & 511u) * CIN + ii];
#pragma unroll
        for (int o = 0; o < COUT; ++o)
            acc[o] = fmaf(hsv, edge_w(a, wb[o], wv[o]), acc[o]);
    }

    __shared__ float red[TUSED * COUT];
    if (t < TUSED) {
#pragma unroll
        for (int o = 0; o < COUT; ++o) red[tc * COUT + o] = acc[o];
    }
    __syncthreads();
    float* __restrict__ out = partial + ((size_t)chunk * NROIS + dst) * COUT;
    if (t < COUT) {
        float tot = 0.f;
#pragma unroll 8
        for (int k = 0; k < TUSED; ++k) tot += red[k * COUT + t];
        out[t] = tot;
    }
}

// combine chunks + mean + root term + bias + relu
template <int CIN, int COUT, int SPLIT>
__global__ __launch_bounds__(256) void node_kernel(
    const float* __restrict__ hin, const float* __restrict__ partial,
    const int* __restrict__ start, const float* __restrict__ root,
    const float* __restrict__ bias, float* __restrict__ hout)
{
    int t = blockIdx.x * 256 + threadIdx.x;
    if (t >= NROIS * COUT) return;
    int i = t / COUT, o = t - i * COUT;
    float s = 0.f;
#pragma unroll
    for (int c = 0; c < SPLIT; ++c) s += partial[((size_t)c * NROIS + i) * COUT + o];
    int cnt = start[i + 1] - start[i];
    float aggr = s / fmaxf((float)cnt, 1.f);
    float r = bias[o];
#pragma unroll 4
    for (int k = 0; k < CIN; ++k) r = fmaf(hin[i * CIN + k], root[k * COUT + o], r);
    hout[t] = fmaxf(aggr + r, 0.f);
}

// cbt[i,j] = sum_k |h[i,k]-h[j,k]|, h: [512,5] staged in LDS, block per row i
__global__ __launch_bounds__(256) void cbt_kernel(const float* __restrict__ h,
                                                  float* __restrict__ out)
{
    __shared__ float sh[NROIS * 5];
    for (int t = threadIdx.x; t < NROIS * 5; t += 256) sh[t] = h[t];
    __syncthreads();
    const int i = blockIdx.x;
    float hi[5];
#pragma unroll
    for (int k = 0; k < 5; ++k) hi[k] = sh[i * 5 + k];
    for (int j = threadIdx.x; j < NROIS; j += 256) {
        float s = 0.f;
#pragma unroll
        for (int k = 0; k < 5; ++k) s += fabsf(hi[k] - sh[j * 5 + k]);
        out[i * NROIS + j] = s;
    }
}

// ---------------------------------------------------------------------------
template <bool PACKED>
static void run_layers(const float* x, const float* ea, const unsigned* er,
                       const float* lw1, const float* lb1, const float* root1, const float* b1,
                       const float* lw2, const float* lb2, const float* root2, const float* b2,
                       const float* lw3, const float* lb3, const float* root3, const float* b3,
                       const float* eas, const unsigned* perm, const int* start,
                       float* part, float* h1, float* h2, float* h3,
                       hipStream_t stream)
{
    edge_aggr1_kernel<36, 7, 256, 8, PACKED><<<dim3(8, NROIS), 256, 0, stream>>>(
        eas, ea, perm, start, lw1, lb1, x, part);
    node_kernel<1, 36, 8><<<(NROIS * 36 + 255) / 256, 256, 0, stream>>>(
        x, part, start, root1, b1, h1);
    edge_aggr_kernel<36, 24, 8, 128, 8, PACKED><<<dim3(8, NROIS), 128, 0, stream>>>(
        eas, ea, perm, start, lw2, lb2, h1, part);
    node_kernel<36, 24, 8><<<(NROIS * 24 + 255) / 256, 256, 0, stream>>>(
        h1, part, start, root2, b2, h2);
    edge_aggr3_kernel<24, 5, 5, 128, 8, PACKED><<<dim3(8, NROIS), 128, 0, stream>>>(
        eas, ea, perm, start, lw3, lb3, h2, part);
    node_kernel<24, 5, 8><<<(NROIS * 5 + 255) / 256, 256, 0, stream>>>(
        h2, part, start, root3, b3, h3);
}

extern "C" void kernel_launch(void* const* d_in, const int* in_sizes, int n_in,
                              void* d_out, int out_size, void* d_ws, size_t ws_size,
                              hipStream_t stream)
{
    const float*    x     = (const float*)d_in[0];
    const float*    ea    = (const float*)d_in[1];
    const unsigned* er    = (const unsigned*)d_in[2];
    const float*    lw1   = (const float*)d_in[3];
    const float*    lb1   = (const float*)d_in[4];
    const float*    root1 = (const float*)d_in[5];
    const float*    b1    = (const float*)d_in[6];
    const float*    lw2   = (const float*)d_in[7];
    const float*    lb2   = (const float*)d_in[8];
    const float*    root2 = (const float*)d_in[9];
    const float*    b2    = (const float*)d_in[10];
    const float*    lw3   = (const float*)d_in[11];
    const float*    lb3   = (const float*)d_in[12];
    const float*    root3 = (const float*)d_in[13];
    const float*    b3    = (const float*)d_in[14];

    const size_t easN  = (size_t)NEDGES * 8;                 // floats
    const size_t restN = 18432 + 12288 + 2560 + 147456 + 513 + 512 + NEDGES;
    const size_t needPacked = (easN + restN) * 4;
    const int packed = (ws_size >= needPacked) ? 1 : 0;

    float* ws   = (float*)d_ws;
    float* eas  = ws;                                  // 8 MB (packed mode only)
    float* rest = packed ? (ws + easN) : ws;
    float* h1   = rest;                 // 512*36
    float* h2   = h1 + NROIS * 36;      // 512*24
    float* h3   = h2 + NROIS * 24;      // 512*5
    float* part = h3 + NROIS * 5;       // 147456 floats (also gpart scratch)
    int* gpart  = (int*)part;           // 256*512 ints (512 KB), pre-layer only
    int* start  = (int*)(part + 147456);
    int* cursor = start + NROIS + 1;    // 512
    unsigned* perm = (unsigned*)(cursor + NROIS);      // 262144

    // --- counting sort by dst + fused edge-attr pack (reused by all layers) ---
    hist_kernel<<<NEDGES / 1024, 256, 0, stream>>>(er, gpart);
    scan_kernel<<<1, 512, 0, stream>>>(gpart, start, cursor);
    scatter_kernel<<<NEDGES / 1024, 256, 0, stream>>>(er, ea, cursor, perm, eas, packed);

    if (packed)
        run_layers<true>(x, ea, er, lw1, lb1, root1, b1, lw2, lb2, root2, b2,
                         lw3, lb3, root3, b3, eas, perm, start, part, h1, h2, h3, stream);
    else
        run_layers<false>(x, ea, er, lw1, lb1, root1, b1, lw2, lb2, root2, b2,
                          lw3, lb3, root3, b3, eas, perm, start, part, h1, h2, h3, stream);

    // --- pairwise L1 distance tail ---
    cbt_kernel<<<NROIS, 256, 0, stream>>>(h3, (float*)d_out);
}